// Round 9
// baseline (7182.922 us; speedup 1.0000x reference)
//
#include <hip/hip_runtime.h>

// Problem constants
#define BB 16
#define TT 4096
#define DD 256     // DIM
#define HH 128     // hidden
#define G3 384     // 3*H
#define MM (BB*TT) // 65536 rows

typedef unsigned short u16;
typedef unsigned int u32;
typedef __attribute__((ext_vector_type(8))) short short8;  // 8 bf16 (4 VGPRs)
typedef __attribute__((ext_vector_type(4))) float f32x4;
typedef __attribute__((ext_vector_type(2))) unsigned int u32x2;
typedef __attribute__((ext_vector_type(4))) unsigned int u32x4;

__device__ __forceinline__ float bf2f(u16 u) {
    return __uint_as_float(((u32)u) << 16);
}
__device__ __forceinline__ u16 f2bf(float f) {
    u32 u = __float_as_uint(f);
    u32 lsb = (u >> 16) & 1u;
    u += 0x7fffu + lsb;      // RNE
    return (u16)(u >> 16);
}

// v_cvt_pk_bf16_f32: packs bf16(x) in low16, bf16(y) in high16.
__device__ __forceinline__ u32 cvt_pk2(float x, float y) {
    u32 pk;
    asm("v_cvt_pk_bf16_f32 %0, %1, %2" : "=v"(pk) : "v"(x), "v"(y));
    return pk;
}
// One-float variant (low 16 bits valid).
__device__ __forceinline__ u32 cvt_bf16(float f) {
    u32 pk;
    asm("v_cvt_pk_bf16_f32 %0, %1, %2" : "=v"(pk) : "v"(f), "v"(f));
    return pk;
}
// Convert 2 fp32 -> packed bf16 hi-pair + packed bf16 residual(lo)-pair.
__device__ __forceinline__ void cvt2_hilo(float x, float y, u32& hi, u32& lo) {
    u32 h = cvt_pk2(x, y);
    float rx = x - __uint_as_float(h << 16);
    float ry = y - __uint_as_float(h & 0xffff0000u);
    hi = h;
    lo = cvt_pk2(rx, ry);
}

// ---------------- Input-projection GEMM: 3-term bf16 MFMA ----------------
// (verified round 8: ~104 us/layer, byte-identical here)
#define GBM 128
#define GBN 128
#define GBK 32
#define APAD 40   // u16 row stride (80 B, 16B-aligned; breaks pow2 bank alias)

__global__ __launch_bounds__(256, 2) void gemm_in(const float* __restrict__ X,
                                                  const float* __restrict__ Wi,
                                                  float* __restrict__ XG) {
    __shared__ __align__(16) u16 Ahi[GBM][APAD];
    __shared__ __align__(16) u16 Alo[GBM][APAD];
    __shared__ __align__(16) u16 Bhi[GBN][APAD];   // transposed: [n][k]
    __shared__ __align__(16) u16 Blo[GBN][APAD];

    const int tid = threadIdx.x;
    const int m0  = blockIdx.y * GBM;
    const int gc0 = blockIdx.x * GBN;          // 0..767 in steps of 128
    const int dir = (gc0 >= G3) ? 1 : 0;
    const int n0  = gc0 - dir * G3;            // 0,128,256
    const float* Wd = Wi + (size_t)dir * DD * G3;

    const int lane = tid & 63;
    const int wv   = tid >> 6;    // 0..3
    const int wr   = wv >> 1;     // wave-row: owns rows [wr*64, wr*64+64)
    const int wc   = wv & 1;      // wave-col: owns cols [wc*64, wc*64+64)
    const int q    = lane >> 4;
    const int c    = lane & 15;

    f32x4 acc[4][4];
    #pragma unroll
    for (int i = 0; i < 4; ++i)
        #pragma unroll
        for (int j = 0; j < 4; ++j) acc[i][j] = (f32x4){0.f, 0.f, 0.f, 0.f};

    const int bn  = tid & 127;
    const int bkh = (tid >> 7) * 16;

    for (int k0 = 0; k0 < DD; k0 += GBK) {
        #pragma unroll
        for (int p = 0; p < 4; ++p) {
            int idx = tid + p * 256;           // 0..1023
            int row = idx >> 3;                // 0..127
            int k4  = (idx & 7) * 4;           // 0,4,...,28
            float4 v = *(const float4*)(X + (size_t)(m0 + row) * DD + k0 + k4);
            u32 h01, l01, h23, l23;
            cvt2_hilo(v.x, v.y, h01, l01);
            cvt2_hilo(v.z, v.w, h23, l23);
            *(u32x2*)(&Ahi[row][k4]) = (u32x2){h01, h23};
            *(u32x2*)(&Alo[row][k4]) = (u32x2){l01, l23};
        }
        {
            float bv[16];
            #pragma unroll
            for (int j = 0; j < 16; ++j)
                bv[j] = Wd[(size_t)(k0 + bkh + j) * G3 + n0 + bn];
            u32 h[8], l[8];
            #pragma unroll
            for (int j = 0; j < 8; ++j)
                cvt2_hilo(bv[2 * j], bv[2 * j + 1], h[j], l[j]);
            *(u32x4*)(&Bhi[bn][bkh + 0]) = (u32x4){h[0], h[1], h[2], h[3]};
            *(u32x4*)(&Bhi[bn][bkh + 8]) = (u32x4){h[4], h[5], h[6], h[7]};
            *(u32x4*)(&Blo[bn][bkh + 0]) = (u32x4){l[0], l[1], l[2], l[3]};
            *(u32x4*)(&Blo[bn][bkh + 8]) = (u32x4){l[4], l[5], l[6], l[7]};
        }
        __syncthreads();
        short8 afh[4], afl[4], bfh[4], bfl[4];
        #pragma unroll
        for (int i = 0; i < 4; ++i) {
            afh[i] = *(const short8*)(&Ahi[wr * 64 + i * 16 + c][q * 8]);
            afl[i] = *(const short8*)(&Alo[wr * 64 + i * 16 + c][q * 8]);
            bfh[i] = *(const short8*)(&Bhi[wc * 64 + i * 16 + c][q * 8]);
            bfl[i] = *(const short8*)(&Blo[wc * 64 + i * 16 + c][q * 8]);
        }
        #pragma unroll
        for (int i = 0; i < 4; ++i)
            #pragma unroll
            for (int j = 0; j < 4; ++j) {
                acc[i][j] = __builtin_amdgcn_mfma_f32_16x16x32_bf16(afh[i], bfh[j], acc[i][j], 0, 0, 0);
                acc[i][j] = __builtin_amdgcn_mfma_f32_16x16x32_bf16(afh[i], bfl[j], acc[i][j], 0, 0, 0);
                acc[i][j] = __builtin_amdgcn_mfma_f32_16x16x32_bf16(afl[i], bfh[j], acc[i][j], 0, 0, 0);
            }
        __syncthreads();
    }
    #pragma unroll
    for (int i = 0; i < 4; ++i) {
        #pragma unroll
        for (int j = 0; j < 4; ++j) {
            const int n = n0 + wc * 64 + j * 16 + c;
            #pragma unroll
            for (int r = 0; r < 4; ++r) {
                const int m = m0 + wr * 64 + i * 16 + q * 4 + r;
                XG[((size_t)dir * MM + m) * G3 + n] = acc[i][j][r];
            }
        }
    }
}

// ---------------- MFMA recurrence, one WG per (dir,batch) ----------------
__device__ __forceinline__ float fast_sigmoid(float x) {
    float e = __expf(-x);
    return __builtin_amdgcn_rcpf(1.f + e);
}
__device__ __forceinline__ float fast_tanh(float x) {
    float e = __expf(2.f * x);
    return 1.f - 2.f * __builtin_amdgcn_rcpf(1.f + e);
}

// hi/lo recombine across the lane<32 / lane>=32 split on the VALU pipe.
// r0 + r1 = g[lane] + g[lane^32] in every lane (verified round 7).
__device__ __forceinline__ float permswap_add(float g) {
    u32 gu = __float_as_uint(g);
    u32x2 r = __builtin_amdgcn_permlane32_swap(gu, gu, false, false);
    return __uint_as_float(r[0]) + __uint_as_float(r[1]);
}

// xg registers for one substep: 2 col-tiles x 3 gates.
struct XG6 { float r0, r1, z0, z1, n0, n1; };
__device__ __forceinline__ XG6 load6(const float* p) {
    XG6 v;
    v.r0 = p[0];   v.r1 = p[16];
    v.z0 = p[128]; v.z1 = p[144];
    v.n0 = p[256]; v.n1 = p[272];
    return v;
}

// grid = 32 (dir,batch); block = 256 (4 waves, 1/SIMD). Wave w owns h-cols
// [32w,32w+32) = 2 col-tiles x 3 gates = 24 MFMAs/wave/step (24/SIMD = the
// issue floor, unchanged).
//
// WHY 4 waves now (vs round 1's failed attempt): round 8's counters show the
// 8-wave step (1045 cyc) = per-wave critical path + the SECOND wave's pipe
// time, because barrier lockstep puts both waves/SIMD in the same phase on
// every shared pipe (DS 384 cyc, MFMA 384, VALU, trans). 4 waves halve the
// DS-pipe traffic (32->16 ds_read_b128/step) and remove the dual-wave
// contention. Round 1's overheads that made this geometry lose are all gone:
// gates dieted (C-init trick, cvt_pk, permlane intrinsic), bank conflicts 0
// (bank-16 pad), prefetch snapshot+in-place (no ring copies).
#define HLO_OFF (2 * HH + 32)   // u16 elements; hlo base = byte 576 = bank 16

__global__ __launch_bounds__(256, 1) void gru_rec(const float* __restrict__ XG,
                                                  const float* __restrict__ Wh,
                                                  const float* __restrict__ bh,
                                                  float* __restrict__ Xout) {
    const int wg   = blockIdx.x;     // 0..31
    const int dir  = wg & 1;
    const int b    = wg >> 1;
    const int tid  = threadIdx.x;
    const int lane = tid & 63;
    const int wave = tid >> 6;       // 0..3
    const int q    = lane >> 4;      // 0..3
    const int c    = lane & 15;
    const int col0 = wave * 32 + c;  // tile0 column; tile1 = col0 + 16

    // [hhi ping|pong (2*HH)] [pad 32] [hlo ping|pong (2*HH)]
    __shared__ __align__(16) u16 hbuf[HLO_OFF + 2 * HH];

    // ---- B-frag preload (Wh), plain bf16: [gate][tile][chunk] ----
    // B layout (16x16x32): n = lane&15, k = (lane>>4)*8 + j
    short8 bfr[3][2][4];
    {
        const float* W = Wh + (size_t)dir * HH * G3;
        #pragma unroll
        for (int g = 0; g < 3; ++g)
            #pragma unroll
            for (int ti = 0; ti < 2; ++ti) {
                const int n = g * 128 + wave * 32 + ti * 16 + c;
                #pragma unroll
                for (int ch = 0; ch < 4; ++ch) {
                    short8 vh;
                    #pragma unroll
                    for (int j = 0; j < 8; ++j) {
                        int k = ch * 32 + q * 8 + j;
                        vh[j] = (short)f2bf(W[(size_t)k * G3 + n]);
                    }
                    bfr[g][ti][ch] = vh;
                }
            }
    }
    // halved biases (C-init is added twice via the hi/lo lane sum)
    float hb[3][2];
    #pragma unroll
    for (int g = 0; g < 3; ++g)
        #pragma unroll
        for (int ti = 0; ti < 2; ++ti)
            hb[g][ti] = 0.5f * bh[dir * G3 + g * 128 + wave * 32 + ti * 16 + c];

    // A-frags: rows 0-7 = h_hi, rows 8-15 = h_lo (shared by both tiles).
    short8 a[4];
    #pragma unroll
    for (int ch = 0; ch < 4; ++ch)
        #pragma unroll
        for (int j = 0; j < 8; ++j) a[ch][j] = 0;
    float ho0 = 0.f, ho1 = 0.f;

    // persistent accumulators (elements 1-3 never read after init)
    f32x4 aR0 = {0,0,0,0}, aZ0 = {0,0,0,0}, aN0 = {0,0,0,0};
    f32x4 aR1 = {0,0,0,0}, aZ1 = {0,0,0,0}, aN1 = {0,0,0,0};

    const int t0    = dir ? (TT - 1) : 0;
    const int gstep = dir ? -G3 : G3;   // xg pointer step (floats)
    const int ostep = dir ? -DD : DD;   // out pointer step (floats)

    const float* xp = XG + ((size_t)dir * MM + (size_t)b * TT + t0) * G3 + col0;
    float* op = Xout + ((size_t)b * TT + t0) * DD + dir * HH + col0;

    // per-lane LDS bases (ping-pong + chunk become compile-time offsets)
    const u16* hrd = hbuf + ((c < 8) ? 0 : HLO_OFF) + q * 8;
    u16* hw_hi = hbuf + col0;
    u16* hw_lo = hbuf + HLO_OFF + col0;

    // depth-4 prefetch, in-place reload (no ring copies)
    XG6 x0 = load6(xp);
    XG6 x1 = load6(xp + gstep);
    XG6 x2 = load6(xp + 2 * gstep);
    XG6 x3 = load6(xp + 3 * gstep);
    const float* xpf = xp + 4 * gstep;   // prefetch base (advances 2*gstep twice/iter)

#define SUBSTEP(S, XV, PK)                                                     \
    {                                                                          \
        /* snapshot current xg, then reload XV in place (prefetch t+S+4) */    \
        float xr0 = XV.r0, xr1 = XV.r1, xz0 = XV.z0, xz1 = XV.z1;              \
        float xn0 = XV.n0, xn1 = XV.n1;                                        \
        if (t + (S) + 4 < TT) { XV = load6(xpf + (PK) * gstep); }              \
        /* C-init: elem0 = 0.5*(xg+bias); permswap doubles it back */          \
        aR0[0] = __builtin_fmaf(0.5f, xr0, hb[0][0]);                          \
        aZ0[0] = __builtin_fmaf(0.5f, xz0, hb[1][0]);                          \
        aN0[0] = hb[2][0];                                                     \
        aR1[0] = __builtin_fmaf(0.5f, xr1, hb[0][1]);                          \
        aZ1[0] = __builtin_fmaf(0.5f, xz1, hb[1][1]);                          \
        aN1[0] = hb[2][1];                                                     \
        /* 24 MFMAs: 6 independent depth-4 chains (6-way ILP) */               \
        _Pragma("unroll")                                                      \
        for (int ch = 0; ch < 4; ++ch) {                                       \
            aR0 = __builtin_amdgcn_mfma_f32_16x16x32_bf16(a[ch], bfr[0][0][ch], aR0, 0, 0, 0); \
            aZ0 = __builtin_amdgcn_mfma_f32_16x16x32_bf16(a[ch], bfr[1][0][ch], aZ0, 0, 0, 0); \
            aN0 = __builtin_amdgcn_mfma_f32_16x16x32_bf16(a[ch], bfr[2][0][ch], aN0, 0, 0, 0); \
            aR1 = __builtin_amdgcn_mfma_f32_16x16x32_bf16(a[ch], bfr[0][1][ch], aR1, 0, 0, 0); \
            aZ1 = __builtin_amdgcn_mfma_f32_16x16x32_bf16(a[ch], bfr[1][1][ch], aZ1, 0, 0, 0); \
            aN1 = __builtin_amdgcn_mfma_f32_16x16x32_bf16(a[ch], bfr[2][1][ch], aN1, 0, 0, 0); \
        }                                                                      \
        float hn0, hn1;                                                        \
        {                                                                      \
            float pr = permswap_add(aR0[0]);                                   \
            float pz = permswap_add(aZ0[0]);                                   \
            float pm = permswap_add(aN0[0]);                                   \
            float rg = fast_sigmoid(pr);                                       \
            float zg = fast_sigmoid(pz);                                       \
            float ng = fast_tanh(xn0 + rg * pm);                               \
            hn0 = (1.f - zg) * ng + zg * ho0;                                  \
            ho0 = hn0;                                                         \
        }                                                                      \
        {                                                                      \
            float pr = permswap_add(aR1[0]);                                   \
            float pz = permswap_add(aZ1[0]);                                   \
            float pm = permswap_add(aN1[0]);                                   \
            float rg = fast_sigmoid(pr);                                       \
            float zg = fast_sigmoid(pz);                                       \
            float ng = fast_tanh(xn1 + rg * pm);                               \
            hn1 = (1.f - zg) * ng + zg * ho1;                                  \
            ho1 = hn1;                                                         \
        }                                                                      \
        /* hi/lo split for both columns */                                     \
        u32 pk_hi0 = cvt_bf16(hn0);                                            \
        u32 pk_hi1 = cvt_bf16(hn1);                                            \
        float lo_f0 = hn0 - __uint_as_float(pk_hi0 << 16);                     \
        float lo_f1 = hn1 - __uint_as_float(pk_hi1 << 16);                     \
        u32 pk_lo0 = cvt_bf16(lo_f0);                                          \
        u32 pk_lo1 = cvt_bf16(lo_f1);                                          \
        const int pb = ((S) + 1) & 1;                                          \
        if (q == 0) {                                                          \
            op[(S) * ostep]      = hn0;                                        \
            op[(S) * ostep + 16] = hn1;                                        \
            hw_hi[pb * HH]      = (u16)pk_hi0;                                 \
            hw_hi[pb * HH + 16] = (u16)pk_hi1;                                 \
        } else if (q == 1) {                                                   \
            hw_lo[pb * HH]      = (u16)pk_lo0;                                 \
            hw_lo[pb * HH + 16] = (u16)pk_lo1;                                 \
        }                                                                      \
        asm volatile("s_waitcnt lgkmcnt(0)\n\ts_barrier" ::: "memory");        \
        if (t + (S) + 1 < TT) {                                                \
            a[0] = *(const short8*)(hrd + pb * HH + 0);                        \
            a[1] = *(const short8*)(hrd + pb * HH + 32);                       \
            a[2] = *(const short8*)(hrd + pb * HH + 64);                       \
            a[3] = *(const short8*)(hrd + pb * HH + 96);                       \
        }                                                                      \
    }

    for (int t = 0; t < TT; t += 4) {
        SUBSTEP(0, x0, 0)
        SUBSTEP(1, x1, 1)
        xpf += 2 * gstep;
        SUBSTEP(2, x2, 0)
        SUBSTEP(3, x3, 1)
        xpf += 2 * gstep;
        op += 4 * ostep;
    }
#undef SUBSTEP
}

// ---------------- Launch ----------------
// ws: XG only = 2*65536*384*4 = 201.3 MB. Inter-layer activations ping-pong
// through d_out (each layer fully rewrites it before the next reads it).
extern "C" void kernel_launch(void* const* d_in, const int* in_sizes, int n_in,
                              void* d_out, int out_size, void* d_ws, size_t ws_size,
                              hipStream_t stream) {
    const float* x  = (const float*)d_in[0];   // [16,4096,256]
    const float* Wi = (const float*)d_in[1];   // [3,2,256,384]
    const float* Wh = (const float*)d_in[2];   // [3,2,128,384]
    const float* bh = (const float*)d_in[3];   // [3,2,384]
    float* out = (float*)d_out;                // [16,4096,256]

    float* XG = (float*)d_ws;                  // [2, 65536, 384] fp32

    for (int l = 0; l < 3; ++l) {
        const float* in  = (l == 0) ? x : out;
        const float* Wil = Wi + (size_t)l * 2 * DD * G3;
        const float* Whl = Wh + (size_t)l * 2 * HH * G3;
        const float* bhl = bh + (size_t)l * 2 * G3;

        gemm_in<<<dim3(6, MM / GBM), 256, 0, stream>>>(in, Wil, XG);
        gru_rec<<<32, 256, 0, stream>>>(XG, Whl, bhl, out);
    }
}

// Round 10
// 5295.439 us; speedup vs baseline: 1.3564x; 1.3564x over previous
//
#include <hip/hip_runtime.h>

// Problem constants
#define BB 16
#define TT 4096
#define DD 256     // DIM
#define HH 128     // hidden
#define G3 384     // 3*H
#define MM (BB*TT) // 65536 rows

typedef unsigned short u16;
typedef unsigned int u32;
typedef __attribute__((ext_vector_type(8))) short short8;  // 8 bf16 (4 VGPRs)
typedef __attribute__((ext_vector_type(4))) float f32x4;
typedef __attribute__((ext_vector_type(2))) unsigned int u32x2;
typedef __attribute__((ext_vector_type(4))) unsigned int u32x4;

__device__ __forceinline__ float bf2f(u16 u) {
    return __uint_as_float(((u32)u) << 16);
}
__device__ __forceinline__ u16 f2bf(float f) {
    u32 u = __float_as_uint(f);
    u32 lsb = (u >> 16) & 1u;
    u += 0x7fffu + lsb;      // RNE
    return (u16)(u >> 16);
}

// v_cvt_pk_bf16_f32: packs bf16(x) in low16, bf16(y) in high16.
__device__ __forceinline__ u32 cvt_pk2(float x, float y) {
    u32 pk;
    asm("v_cvt_pk_bf16_f32 %0, %1, %2" : "=v"(pk) : "v"(x), "v"(y));
    return pk;
}
// One-float variant (low 16 bits valid).
__device__ __forceinline__ u32 cvt_bf16(float f) {
    u32 pk;
    asm("v_cvt_pk_bf16_f32 %0, %1, %2" : "=v"(pk) : "v"(f), "v"(f));
    return pk;
}
// Convert 2 fp32 -> packed bf16 hi-pair + packed bf16 residual(lo)-pair.
__device__ __forceinline__ void cvt2_hilo(float x, float y, u32& hi, u32& lo) {
    u32 h = cvt_pk2(x, y);
    float rx = x - __uint_as_float(h << 16);
    float ry = y - __uint_as_float(h & 0xffff0000u);
    hi = h;
    lo = cvt_pk2(rx, ry);
}

// ---------------- Input-projection GEMM: 3-term bf16 MFMA ----------------
// (verified round 8: ~104 us/layer, byte-identical here)
#define GBM 128
#define GBN 128
#define GBK 32
#define APAD 40   // u16 row stride (80 B, 16B-aligned; breaks pow2 bank alias)

__global__ __launch_bounds__(256, 2) void gemm_in(const float* __restrict__ X,
                                                  const float* __restrict__ Wi,
                                                  float* __restrict__ XG) {
    __shared__ __align__(16) u16 Ahi[GBM][APAD];
    __shared__ __align__(16) u16 Alo[GBM][APAD];
    __shared__ __align__(16) u16 Bhi[GBN][APAD];   // transposed: [n][k]
    __shared__ __align__(16) u16 Blo[GBN][APAD];

    const int tid = threadIdx.x;
    const int m0  = blockIdx.y * GBM;
    const int gc0 = blockIdx.x * GBN;          // 0..767 in steps of 128
    const int dir = (gc0 >= G3) ? 1 : 0;
    const int n0  = gc0 - dir * G3;            // 0,128,256
    const float* Wd = Wi + (size_t)dir * DD * G3;

    const int lane = tid & 63;
    const int wv   = tid >> 6;    // 0..3
    const int wr   = wv >> 1;     // wave-row: owns rows [wr*64, wr*64+64)
    const int wc   = wv & 1;      // wave-col: owns cols [wc*64, wc*64+64)
    const int q    = lane >> 4;
    const int c    = lane & 15;

    f32x4 acc[4][4];
    #pragma unroll
    for (int i = 0; i < 4; ++i)
        #pragma unroll
        for (int j = 0; j < 4; ++j) acc[i][j] = (f32x4){0.f, 0.f, 0.f, 0.f};

    const int bn  = tid & 127;
    const int bkh = (tid >> 7) * 16;

    for (int k0 = 0; k0 < DD; k0 += GBK) {
        #pragma unroll
        for (int p = 0; p < 4; ++p) {
            int idx = tid + p * 256;           // 0..1023
            int row = idx >> 3;                // 0..127
            int k4  = (idx & 7) * 4;           // 0,4,...,28
            float4 v = *(const float4*)(X + (size_t)(m0 + row) * DD + k0 + k4);
            u32 h01, l01, h23, l23;
            cvt2_hilo(v.x, v.y, h01, l01);
            cvt2_hilo(v.z, v.w, h23, l23);
            *(u32x2*)(&Ahi[row][k4]) = (u32x2){h01, h23};
            *(u32x2*)(&Alo[row][k4]) = (u32x2){l01, l23};
        }
        {
            float bv[16];
            #pragma unroll
            for (int j = 0; j < 16; ++j)
                bv[j] = Wd[(size_t)(k0 + bkh + j) * G3 + n0 + bn];
            u32 h[8], l[8];
            #pragma unroll
            for (int j = 0; j < 8; ++j)
                cvt2_hilo(bv[2 * j], bv[2 * j + 1], h[j], l[j]);
            *(u32x4*)(&Bhi[bn][bkh + 0]) = (u32x4){h[0], h[1], h[2], h[3]};
            *(u32x4*)(&Bhi[bn][bkh + 8]) = (u32x4){h[4], h[5], h[6], h[7]};
            *(u32x4*)(&Blo[bn][bkh + 0]) = (u32x4){l[0], l[1], l[2], l[3]};
            *(u32x4*)(&Blo[bn][bkh + 8]) = (u32x4){l[4], l[5], l[6], l[7]};
        }
        __syncthreads();
        short8 afh[4], afl[4], bfh[4], bfl[4];
        #pragma unroll
        for (int i = 0; i < 4; ++i) {
            afh[i] = *(const short8*)(&Ahi[wr * 64 + i * 16 + c][q * 8]);
            afl[i] = *(const short8*)(&Alo[wr * 64 + i * 16 + c][q * 8]);
            bfh[i] = *(const short8*)(&Bhi[wc * 64 + i * 16 + c][q * 8]);
            bfl[i] = *(const short8*)(&Blo[wc * 64 + i * 16 + c][q * 8]);
        }
        #pragma unroll
        for (int i = 0; i < 4; ++i)
            #pragma unroll
            for (int j = 0; j < 4; ++j) {
                acc[i][j] = __builtin_amdgcn_mfma_f32_16x16x32_bf16(afh[i], bfh[j], acc[i][j], 0, 0, 0);
                acc[i][j] = __builtin_amdgcn_mfma_f32_16x16x32_bf16(afh[i], bfl[j], acc[i][j], 0, 0, 0);
                acc[i][j] = __builtin_amdgcn_mfma_f32_16x16x32_bf16(afl[i], bfh[j], acc[i][j], 0, 0, 0);
            }
        __syncthreads();
    }
    #pragma unroll
    for (int i = 0; i < 4; ++i) {
        #pragma unroll
        for (int j = 0; j < 4; ++j) {
            const int n = n0 + wc * 64 + j * 16 + c;
            #pragma unroll
            for (int r = 0; r < 4; ++r) {
                const int m = m0 + wr * 64 + i * 16 + q * 4 + r;
                XG[((size_t)dir * MM + m) * G3 + n] = acc[i][j][r];
            }
        }
    }
}

// ---------------- MFMA recurrence, one WG per (dir,batch) ----------------
__device__ __forceinline__ float fast_sigmoid(float x) {
    float e = __expf(-x);
    return __builtin_amdgcn_rcpf(1.f + e);
}
__device__ __forceinline__ float fast_tanh(float x) {
    float e = __expf(2.f * x);
    return 1.f - 2.f * __builtin_amdgcn_rcpf(1.f + e);
}

struct XG3 { float r, z, n; };
__device__ __forceinline__ XG3 load3(const float* p) {
    XG3 v;
    v.r = p[0];
    v.z = p[128];
    v.n = p[256];
    return v;
}

// grid = 32 (dir,batch); block = 512 (8 waves, 2/SIMD — verified geometry:
// 1/SIMD measured +28% step time twice, rounds 1 & 9). Wave w owns h-cols
// [16w,16w+16); 3 gate tiles = 12 MFMAs/wave/step (24/SIMD, 384-cyc floor).
//
// Round-10 change: EVEN/ODD row interleave kills the permlane recombine.
// A rows: even = h_hi, odd = h_lo (replicated). Then for every lane,
// acc reg0 (row q*4, even) = hi@W and reg1 (row q*4+1, odd) = lo@W —
// the hi/lo recombine is a LOCAL acc[0]+acc[1] add: no permlane32_swap
// (3 fewer cross-lane ops + latency off the serial critical path), no
// halved-bias bookkeeping. C-init: reg0 = xg+bias, reg1 = 0 per substep;
// regs 2-3 accumulate stale garbage, never read, stay finite.
// A-frag source select: c&1 ? hlo : hhi. Per quad: 8 lanes broadcast from
// hhi (bank 0) + 8 from hlo (bank 16, via the 64B pad) -> conflict-free
// (round-7/8 measured 0 conflicts with the same two bases).
#define HLO_OFF (2 * HH + 32)   // u16 elements; hlo base = byte 576 = bank 16

__global__ __launch_bounds__(512, 1) void gru_rec(const float* __restrict__ XG,
                                                  const float* __restrict__ Wh,
                                                  const float* __restrict__ bh,
                                                  float* __restrict__ Xout) {
    const int wg   = blockIdx.x;     // 0..31
    const int dir  = wg & 1;
    const int b    = wg >> 1;
    const int tid  = threadIdx.x;
    const int lane = tid & 63;
    const int wave = tid >> 6;       // 0..7
    const int q    = lane >> 4;      // 0..3
    const int c    = lane & 15;
    const int hcol = wave * 16 + c;  // 0..127

    // [hhi ping|pong (2*HH)] [pad 32] [hlo ping|pong (2*HH)]
    __shared__ __align__(16) u16 hbuf[HLO_OFF + 2 * HH];

    // ---- B-frag preload (Wh), plain bf16 ----
    // B layout (16x16x32): n = lane&15, k = (lane>>4)*8 + j
    short8 bfr[3][4];
    {
        const float* W = Wh + (size_t)dir * HH * G3;
        #pragma unroll
        for (int g = 0; g < 3; ++g) {
            const int n = g * 128 + hcol;
            #pragma unroll
            for (int ch = 0; ch < 4; ++ch) {
                short8 vh;
                #pragma unroll
                for (int j = 0; j < 8; ++j) {
                    int k = ch * 32 + q * 8 + j;
                    vh[j] = (short)f2bf(W[(size_t)k * G3 + n]);
                }
                bfr[g][ch] = vh;
            }
        }
    }
    // full biases (no permswap double-count anymore)
    float hb[3];
    #pragma unroll
    for (int g = 0; g < 3; ++g) hb[g] = bh[dir * G3 + g * 128 + hcol];

    // A-frags: even rows = h_hi, odd rows = h_lo. Lane's row m = c, so
    // odd-c lanes read from hlo, even-c from hhi. Zero at t=0.
    short8 a[4];
    #pragma unroll
    for (int ch = 0; ch < 4; ++ch)
        #pragma unroll
        for (int j = 0; j < 8; ++j) a[ch][j] = 0;
    float ho = 0.f;                  // h_old at this wave's column (fp32)

    // persistent accumulators (regs 2-3 never read after init)
    f32x4 accR = {0.f, 0.f, 0.f, 0.f};
    f32x4 accZ = {0.f, 0.f, 0.f, 0.f};
    f32x4 accN = {0.f, 0.f, 0.f, 0.f};

    const int t0    = dir ? (TT - 1) : 0;
    const int gstep = dir ? -G3 : G3;   // xg pointer step (floats)
    const int ostep = dir ? -DD : DD;   // out pointer step (floats)

    const float* xp = XG + ((size_t)dir * MM + (size_t)b * TT + t0) * G3 + hcol;
    float* op = Xout + ((size_t)b * TT + t0) * DD + dir * HH + hcol;

    // per-lane LDS bases (ping-pong + chunk become compile-time offsets)
    const u16* hrd = hbuf + ((c & 1) ? HLO_OFF : 0) + q * 8;
    u16* hw_hi = hbuf + hcol;
    u16* hw_lo = hbuf + HLO_OFF + hcol;

    // depth-4 prefetch, in-place reload (no ring copies)
    XG3 x0 = load3(xp);
    XG3 x1 = load3(xp + gstep);
    XG3 x2 = load3(xp + 2 * gstep);
    XG3 x3 = load3(xp + 3 * gstep);
    const float* xpf = xp + 4 * gstep;   // prefetch base (advances 2*gstep twice/iter)

#define SUBSTEP(S, XV, PK)                                                     \
    {                                                                          \
        /* snapshot current xg, then reload XV in place (prefetch t+S+4) */    \
        float xr = XV.r, xz = XV.z, xn = XV.n;                                 \
        if (t + (S) + 4 < TT) { XV = load3(xpf + (PK) * gstep); }              \
        /* C-init: reg0 (even row) = xg+bias gets hi@W; reg1 (odd) = lo@W */   \
        accR[0] = xr + hb[0];                                                  \
        accZ[0] = xz + hb[1];                                                  \
        accN[0] = hb[2];                                                       \
        accR[1] = 0.f;                                                         \
        accZ[1] = 0.f;                                                         \
        accN[1] = 0.f;                                                         \
        /* 12 MFMAs: 3 independent depth-4 chains */                           \
        _Pragma("unroll")                                                      \
        for (int ch = 0; ch < 4; ++ch) {                                       \
            accR = __builtin_amdgcn_mfma_f32_16x16x32_bf16(a[ch], bfr[0][ch], accR, 0, 0, 0); \
            accZ = __builtin_amdgcn_mfma_f32_16x16x32_bf16(a[ch], bfr[1][ch], accZ, 0, 0, 0); \
            accN = __builtin_amdgcn_mfma_f32_16x16x32_bf16(a[ch], bfr[2][ch], accN, 0, 0, 0); \
        }                                                                      \
        /* local hi+lo recombine (no cross-lane op) */                         \
        float pr = accR[0] + accR[1];                                          \
        float pz = accZ[0] + accZ[1];                                          \
        float pm = accN[0] + accN[1];                                          \
        float rg = fast_sigmoid(pr);                                           \
        float zg = fast_sigmoid(pz);                                           \
        float ng = fast_tanh(xn + rg * pm);                                    \
        float hn = (1.f - zg) * ng + zg * ho;                                  \
        ho = hn;                                                               \
        /* hi/lo split: 1 cvt + shift + sub + 1 cvt */                         \
        u32 pk_hi = cvt_bf16(hn);                                              \
        float lo_f = hn - __uint_as_float(pk_hi << 16);                        \
        u32 pk_lo = cvt_bf16(lo_f);                                            \
        const int pb = ((S) + 1) & 1;                                          \
        if (q == 0) {                                                          \
            op[(S) * ostep] = hn;                                              \
            hw_hi[pb * HH]  = (u16)pk_hi;                                      \
        } else if (q == 1) {                                                   \
            hw_lo[pb * HH]  = (u16)pk_lo;                                      \
        }                                                                      \
        asm volatile("s_waitcnt lgkmcnt(0)\n\ts_barrier" ::: "memory");        \
        if (t + (S) + 1 < TT) {                                                \
            a[0] = *(const short8*)(hrd + pb * HH + 0);                        \
            a[1] = *(const short8*)(hrd + pb * HH + 32);                       \
            a[2] = *(const short8*)(hrd + pb * HH + 64);                       \
            a[3] = *(const short8*)(hrd + pb * HH + 96);                       \
        }                                                                      \
    }

    for (int t = 0; t < TT; t += 4) {
        SUBSTEP(0, x0, 0)
        SUBSTEP(1, x1, 1)
        xpf += 2 * gstep;
        SUBSTEP(2, x2, 0)
        SUBSTEP(3, x3, 1)
        xpf += 2 * gstep;
        op += 4 * ostep;
    }
#undef SUBSTEP
}

// ---------------- Launch ----------------
// ws: XG only = 2*65536*384*4 = 201.3 MB. Inter-layer activations ping-pong
// through d_out (each layer fully rewrites it before the next reads it).
extern "C" void kernel_launch(void* const* d_in, const int* in_sizes, int n_in,
                              void* d_out, int out_size, void* d_ws, size_t ws_size,
                              hipStream_t stream) {
    const float* x  = (const float*)d_in[0];   // [16,4096,256]
    const float* Wi = (const float*)d_in[1];   // [3,2,256,384]
    const float* Wh = (const float*)d_in[2];   // [3,2,128,384]
    const float* bh = (const float*)d_in[3];   // [3,2,384]
    float* out = (float*)d_out;                // [16,4096,256]

    float* XG = (float*)d_ws;                  // [2, 65536, 384] fp32

    for (int l = 0; l < 3; ++l) {
        const float* in  = (l == 0) ? x : out;
        const float* Wil = Wi + (size_t)l * 2 * DD * G3;
        const float* Whl = Wh + (size_t)l * 2 * HH * G3;
        const float* bhl = bh + (size_t)l * 2 * G3;

        gemm_in<<<dim3(6, MM / GBM), 256, 0, stream>>>(in, Wil, XG);
        gru_rec<<<32, 512, 0, stream>>>(XG, Whl, bhl, out);
    }
}